// Round 2
// baseline (525.975 us; speedup 1.0000x reference)
//
#include <hip/hip_runtime.h>
#include <hip/hip_bf16.h>
#include <stdint.h>

// out[m,n] = sum_k x[m,k] * (W[n,k] + sum_r down[n,r]*up[r,k]) + bias[n]
// M=8192, N=4096, K=4096, R=16, fp32 I/O.
// Round 5: GEMM switched to v_mfma_f32_32x32x16_bf16 (half the MFMA issues,
// 2382 vs 2075 TF pipe rate). Same 256x256/BK=64/8-wave/4-phase-per-Ktile
// schedule, counted vmcnt, granule-XOR LDS swizzle, setprio, XCD swizzle.
// A/B frag: lane l -> row l&31, k = (l>>5)*8 + j  (16 B ds_read_b128, same as
// the verified 16x16x32 mapping doubled). C/D: col=lane&31,
// row=(reg&3)+8*(reg>>2)+4*(lane>>5)  [m74/m101].

typedef __attribute__((ext_vector_type(4)))  float  floatx4;
typedef __attribute__((ext_vector_type(16))) float  floatx16;
typedef __attribute__((ext_vector_type(8)))  __bf16 bf16x8;

static __device__ __forceinline__ unsigned short f2bf_rne(float f) {
    union { float f; uint32_t u; } v; v.f = f;
    uint32_t r = v.u + 0x7fffu + ((v.u >> 16) & 1u);
    return (unsigned short)(r >> 16);
}

// ---------------- x fp32 -> bf16, coalesced, 16B stores ----------------
__global__ __launch_bounds__(256) void cvt_x_kernel(const float4* __restrict__ x4,
                                                    uint4* __restrict__ o4,
                                                    int n8) {
    const int stride = gridDim.x * 256;
    for (int i = blockIdx.x * 256 + threadIdx.x; i < n8; i += stride) {
        float4 a = x4[2 * i];
        float4 b = x4[2 * i + 1];
        union { unsigned short s[8]; uint4 v; } o;
        o.s[0] = f2bf_rne(a.x); o.s[1] = f2bf_rne(a.y);
        o.s[2] = f2bf_rne(a.z); o.s[3] = f2bf_rne(a.w);
        o.s[4] = f2bf_rne(b.x); o.s[5] = f2bf_rne(b.y);
        o.s[6] = f2bf_rne(b.z); o.s[7] = f2bf_rne(b.w);
        o4[i] = o.v;
    }
}

// ------------- merged weight: Wb[n,k] = bf16(W[n,k] + sum_r d[n,r]*up[r,k]) -------------
#define MW_ROWS 16
__global__ __launch_bounds__(256) void merge_w_kernel(const float* __restrict__ W,
                                                      const float* __restrict__ down,
                                                      const float* __restrict__ up,
                                                      unsigned short* __restrict__ wb,
                                                      int IN) {
    const int i  = blockIdx.x * 1024 + threadIdx.x * 4;
    const int o0 = blockIdx.y * MW_ROWS;

    float4 u[16];
#pragma unroll
    for (int r = 0; r < 16; r++) u[r] = *(const float4*)(up + r * IN + i);

    for (int o = o0; o < o0 + MW_ROWS; o++) {
        float4 w = *(const float4*)(W + (size_t)o * IN + i);
#pragma unroll
        for (int r = 0; r < 16; r++) {
            const float dr = down[o * 16 + r];   // wave-uniform -> scalar load
            w.x += dr * u[r].x; w.y += dr * u[r].y;
            w.z += dr * u[r].z; w.w += dr * u[r].w;
        }
        union { unsigned short s[4]; uint2 v; } ov;
        ov.s[0] = f2bf_rne(w.x); ov.s[1] = f2bf_rne(w.y);
        ov.s[2] = f2bf_rne(w.z); ov.s[3] = f2bf_rne(w.w);
        *(uint2*)(wb + (size_t)o * IN + i) = ov.v;
    }
}

// ---------------- bf16 gemm_bt, 256x256 tile, BK=64, 32x32x16 MFMA ----------------
#define BM 256
#define BN 256
#define BK 64

static __device__ __forceinline__ void async16(const void* g, void* l) {
    auto* gp = reinterpret_cast<const __attribute__((address_space(1))) uint32_t*>(
        reinterpret_cast<uintptr_t>(g));
    auto* lp = reinterpret_cast<__attribute__((address_space(3))) uint32_t*>(
        reinterpret_cast<uintptr_t>(l));
    __builtin_amdgcn_global_load_lds(gp, lp, 16 /*bytes*/, 0, 0);
}

// LDS map (128 KiB):
//   A: buf*32768 + half*16384      (2 bufs x 2 halves x 128 rows x 64 bf16)
//   B: 65536 + buf*32768 + half*16384
// Row = 128 B = 8 granules of 16 B; logical chunk q of row r lives at granule
// q ^ (r & 7). DMA dest is linear (tid*16); the inverse permutation is applied
// to the per-lane *global* source column.
__global__ __launch_bounds__(512, 2) void gemm_bt_bias_kernel(
    const unsigned short* __restrict__ A,   // bf16 [M][K]  (xb)
    const unsigned short* __restrict__ B,   // bf16 [N][K]  (wb)
    const float* __restrict__ bias,         // [N]
    float* __restrict__ C,                  // [M][N]
    int M, int N, int K) {
    __shared__ __align__(16) unsigned char smem[131072];

    const int tid  = threadIdx.x;
    const int wave = tid >> 6;
    const int lane = tid & 63;
    const int wm   = wave >> 2;      // 0..1 : M-half of tile
    const int wn   = wave & 3;       // 0..3 : N-quarter of tile
    const int l5   = lane & 31;
    const int lhi  = lane >> 5;      // 0..1

    // bijective XCD swizzle (gridDim.x = 512, divisible by 8)
    const int nwg = gridDim.x;
    const int bid = blockIdx.x;
    const int swz = (bid & 7) * (nwg >> 3) + (bid >> 3);
    const int ntn = N / BN;
    const int tileM = (swz / ntn) * BM;
    const int tileN = (swz % ntn) * BN;

    const int nt = K / BK;           // 64, power of two

    // ---- staging: linear LDS dest, pre-swizzled global src ----
    const int trow = tid >> 3;                          // 0..63
    const int tcol = ((tid & 7) ^ (trow & 7)) << 3;     // element offset in row
    const unsigned short* aG = A + (size_t)(tileM + trow) * K + tcol;
    const unsigned short* bG = B + (size_t)(tileN + trow) * K + tcol;
    unsigned char* ldst = smem + tid * 16;

#define STAGE_A(tk, h) do {                                                   \
        const size_t kof = (size_t)(((tk) & (nt - 1)) * BK);                  \
        unsigned char* d = ldst + (((tk) & 1) * 32768 + (h) * 16384);         \
        async16(aG + (size_t)((h) * 128) * K + kof, d);                       \
        async16(aG + (size_t)((h) * 128 + 64) * K + kof, d + 8192);           \
    } while (0)
#define STAGE_B(tk, h) do {                                                   \
        const size_t kof = (size_t)(((tk) & (nt - 1)) * BK);                  \
        unsigned char* d = ldst + (65536 + ((tk) & 1) * 32768 + (h) * 16384); \
        async16(bG + (size_t)((h) * 128) * K + kof, d);                       \
        async16(bG + (size_t)((h) * 128 + 64) * K + kof, d + 8192);           \
    } while (0)

    // ---- fragment read offsets ----
    // A frag (bm, ks): Ab + bm*4096 + (l5*128) + ((ks*2+lhi) ^ (l5&7))*16
    // B frag (bn, ks): Bb + bn*4096 + same granule term
    const int gk  = l5 & 7;
    const int qs0 = ((0 + lhi) ^ gk) << 4;
    const int qs1 = ((2 + lhi) ^ gk) << 4;
    const int qs2 = ((4 + lhi) ^ gk) << 4;
    const int qs3 = ((6 + lhi) ^ gk) << 4;
    const int arowb = l5 * 128;
    const int browb = ((wn & 1) * 64 + l5) * 128;

    floatx16 acc[4][2];
#pragma unroll
    for (int i = 0; i < 4; i++) {
        acc[i][0] = (floatx16)(0.0f);
        acc[i][1] = (floatx16)(0.0f);
    }

    // ---- prologue: kt0 fully staged (8 loads) + kt1.B (4 loads) ----
    STAGE_A(0, 0); STAGE_A(0, 1); STAGE_B(0, 0); STAGE_B(0, 1);
    STAGE_B(1, 0); STAGE_B(1, 1);
    asm volatile("s_waitcnt vmcnt(4)" ::: "memory");   // kt0 landed, kt1.B in flight
    __builtin_amdgcn_s_barrier();

#define MFMA_PHASE(bm)                                                         \
    do {                                                                       \
        acc[bm][0] = __builtin_amdgcn_mfma_f32_32x32x16_bf16(a0, bf00, acc[bm][0], 0, 0, 0); \
        acc[bm][1] = __builtin_amdgcn_mfma_f32_32x32x16_bf16(a0, bf10, acc[bm][1], 0, 0, 0); \
        acc[bm][0] = __builtin_amdgcn_mfma_f32_32x32x16_bf16(a1, bf01, acc[bm][0], 0, 0, 0); \
        acc[bm][1] = __builtin_amdgcn_mfma_f32_32x32x16_bf16(a1, bf11, acc[bm][1], 0, 0, 0); \
        acc[bm][0] = __builtin_amdgcn_mfma_f32_32x32x16_bf16(a2, bf02, acc[bm][0], 0, 0, 0); \
        acc[bm][1] = __builtin_amdgcn_mfma_f32_32x32x16_bf16(a2, bf12, acc[bm][1], 0, 0, 0); \
        acc[bm][0] = __builtin_amdgcn_mfma_f32_32x32x16_bf16(a3, bf03, acc[bm][0], 0, 0, 0); \
        acc[bm][1] = __builtin_amdgcn_mfma_f32_32x32x16_bf16(a3, bf13, acc[bm][1], 0, 0, 0); \
    } while (0)

#define LOAD_A(bm)                                                             \
        a0 = *(const bf16x8*)(Ab + (bm) * 4096 + qs0);                         \
        a1 = *(const bf16x8*)(Ab + (bm) * 4096 + qs1);                         \
        a2 = *(const bf16x8*)(Ab + (bm) * 4096 + qs2);                         \
        a3 = *(const bf16x8*)(Ab + (bm) * 4096 + qs3)

#pragma unroll 2
    for (int kt = 0; kt < nt; ++kt) {
        const int cur = kt & 1;
        const unsigned char* Ab = smem + (cur * 32768 + wm * 16384 + arowb);
        const unsigned char* Bb = smem + (65536 + cur * 32768 + (wn >> 1) * 16384 + browb);

        bf16x8 bf00, bf01, bf02, bf03, bf10, bf11, bf12, bf13;
        bf16x8 a0, a1, a2, a3;

        // ---------- phase 0 : all 8 B frags -> regs, A block 0 ----------
        bf00 = *(const bf16x8*)(Bb + 0 * 4096 + qs0);
        bf01 = *(const bf16x8*)(Bb + 0 * 4096 + qs1);
        bf02 = *(const bf16x8*)(Bb + 0 * 4096 + qs2);
        bf03 = *(const bf16x8*)(Bb + 0 * 4096 + qs3);
        bf10 = *(const bf16x8*)(Bb + 1 * 4096 + qs0);
        bf11 = *(const bf16x8*)(Bb + 1 * 4096 + qs1);
        bf12 = *(const bf16x8*)(Bb + 1 * 4096 + qs2);
        bf13 = *(const bf16x8*)(Bb + 1 * 4096 + qs3);
        LOAD_A(0);
        STAGE_A(kt + 1, 0);                  // other buffer's A: free since kt-1 end
        __builtin_amdgcn_s_barrier();
        __builtin_amdgcn_s_setprio(1);
        MFMA_PHASE(0);
        __builtin_amdgcn_s_setprio(0);
        __builtin_amdgcn_s_barrier();

        // ---------- phase 1 : A block 1 ----------
        LOAD_A(1);
        STAGE_A(kt + 1, 1);
        __builtin_amdgcn_s_barrier();
        __builtin_amdgcn_s_setprio(1);
        MFMA_PHASE(1);
        __builtin_amdgcn_s_setprio(0);
        __builtin_amdgcn_s_barrier();

        // ---------- phase 2 : A block 2 ----------
        LOAD_A(2);
        STAGE_B(kt + 2, 0);                  // current buffer's B: dead after phase 0
        __builtin_amdgcn_s_barrier();
        __builtin_amdgcn_s_setprio(1);
        MFMA_PHASE(2);
        __builtin_amdgcn_s_setprio(0);
        __builtin_amdgcn_s_barrier();

        // ---------- phase 3 : A block 3, counted vmcnt ----------
        LOAD_A(3);
        STAGE_B(kt + 2, 1);
        __builtin_amdgcn_s_barrier();
        __builtin_amdgcn_s_setprio(1);
        MFMA_PHASE(3);
        __builtin_amdgcn_s_setprio(0);
        // all of kt+1 landed; kt+2's 4 B loads stay in flight -- never drain to 0.
        asm volatile("s_waitcnt vmcnt(4)" ::: "memory");
        __builtin_amdgcn_s_barrier();
    }

    // drain the overhanging prefetches before LDS can be reassigned
    asm volatile("s_waitcnt vmcnt(0)" ::: "memory");

    // ---- epilogue: C/D col=lane&31, row=(reg&3)+8*(reg>>2)+4*(lane>>5) ----
    const float bv0 = bias[tileN + wn * 64 + l5];
    const float bv1 = bias[tileN + wn * 64 + 32 + l5];

#pragma unroll
    for (int bm = 0; bm < 4; bm++) {
#pragma unroll
        for (int r = 0; r < 16; r++) {
            const int row = tileM + wm * 128 + bm * 32 + (r & 3) + ((r >> 2) << 3) + (lhi << 2);
            float* crow = C + (size_t)row * N + tileN + wn * 64 + l5;
            crow[0]  = acc[bm][0][r] + bv0;
            crow[32] = acc[bm][1][r] + bv1;
        }
    }
}

extern "C" void kernel_launch(void* const* d_in, const int* in_sizes, int n_in,
                              void* d_out, int out_size, void* d_ws, size_t ws_size,
                              hipStream_t stream) {
    const float* x    = (const float*)d_in[0];
    const float* W    = (const float*)d_in[1];
    const float* bias = (const float*)d_in[2];
    const float* down = (const float*)d_in[3];
    const float* up   = (const float*)d_in[4];
    float* out = (float*)d_out;

    const int IN  = 4096;                 // K
    const int OUT = 4096;                 // N
    const int M   = in_sizes[0] / IN;     // 8192

    unsigned short* xb = (unsigned short*)d_ws;                  // M*K bf16
    unsigned short* wb = xb + (size_t)M * IN;                    // N*K bf16

    const int n8 = M * IN / 8;
    cvt_x_kernel<<<2048, 256, 0, stream>>>((const float4*)x, (uint4*)xb, n8);
    dim3 mgrid(IN / 1024, OUT / MW_ROWS);   // (4, 256)
    merge_w_kernel<<<mgrid, 256, 0, stream>>>(W, down, up, wb, IN);

    dim3 grid((M / BM) * (OUT / BN));   // 32*16 = 512, divisible by 8
    gemm_bt_bias_kernel<<<grid, 512, 0, stream>>>(xb, wb, bias, out, M, OUT, IN);
}